// Round 1
// baseline (7973.490 us; speedup 1.0000x reference)
//
#include <hip/hip_runtime.h>
#include <cmath>

// ConvLSTM2D x2 (Keras semantics), B=8 T=10 H=W=64 Cin=32 F=64.
// fp32 baseline: fused conv(x,Wk)+conv(h,Uk)+b -> gates -> c,h update per step.
// One kernel launch per (layer, timestep); host-side double buffer for h, c in-place.

#define HH 64
#define WW 64
#define FC 64          // filters
#define GC 256         // 4*FC gate channels
#define TILE 32        // pixels (columns) per block
#define PPT 8          // pixels per thread (TILE / 4 pixel-groups)
#define NTHREADS 256

__device__ __forceinline__ float hsig(float v) {
    // Keras hard_sigmoid: clip(0.2*x + 0.5, 0, 1)
    return fminf(fmaxf(fmaf(v, 0.2f, 0.5f), 0.0f), 1.0f);
}

// Accumulate one 'SAME' conv (input I: [HH,WW,CIN] for this batch, weights
// Wt: [KS,KS,CIN,256]) into acc[pixel][gate] for f = cl, pixels pg*PPT..+PPT-1
// of row y, columns x0..x0+TILE-1.
template<int CIN, int KS>
__device__ __forceinline__ void conv_accum(
    const float* __restrict__ I,
    const float* __restrict__ Wt,
    float (&acc)[PPT][4],
    float* lds,
    int y, int x0, int cl, int pg)
{
    constexpr int PAD = KS / 2;
    constexpr int COLS = TILE + 2 * PAD;
    const int tid = threadIdx.x;
    for (int ky = 0; ky < KS; ++ky) {
        int y_in = y + ky - PAD;
        if (y_in < 0 || y_in >= HH) continue;   // block-uniform branch
        __syncthreads();                        // prev LDS users done
        // Stage input row segment (with zero-padded column halo) into LDS.
        const float* row = I + (size_t)y_in * WW * CIN;
        for (int idx = tid; idx < COLS * CIN; idx += NTHREADS) {
            int col = idx / CIN;                // CIN is power of 2 -> shift
            int c   = idx - col * CIN;
            int gcol = x0 - PAD + col;
            lds[idx] = (gcol >= 0 && gcol < WW) ? row[gcol * CIN + c] : 0.0f;
        }
        __syncthreads();
        #pragma unroll
        for (int kx = 0; kx < KS; ++kx) {
            const float* wp = Wt + ((size_t)(ky * KS + kx) * CIN) * GC + cl;
            #pragma unroll 2
            for (int cc = 0; cc < CIN; cc += 4) {
                float4 xv[PPT];
                #pragma unroll
                for (int p = 0; p < PPT; ++p) {
                    int px = pg * PPT + p;
                    // wave-uniform address -> LDS broadcast, no bank conflicts
                    xv[p] = *reinterpret_cast<const float4*>(&lds[(px + kx) * CIN + cc]);
                }
                #pragma unroll
                for (int q = 0; q < 4; ++q) {
                    const float* wq = wp + (size_t)(cc + q) * GC;
                    // lane cl reads consecutive floats -> coalesced 256B
                    float w0 = wq[0];
                    float w1 = wq[64];
                    float w2 = wq[128];
                    float w3 = wq[192];
                    #pragma unroll
                    for (int p = 0; p < PPT; ++p) {
                        float xs = (q == 0) ? xv[p].x : (q == 1) ? xv[p].y
                                 : (q == 2) ? xv[p].z : xv[p].w;
                        acc[p][0] = fmaf(xs, w0, acc[p][0]);
                        acc[p][1] = fmaf(xs, w1, acc[p][1]);
                        acc[p][2] = fmaf(xs, w2, acc[p][2]);
                        acc[p][3] = fmaf(xs, w3, acc[p][3]);
                    }
                }
            }
        }
    }
}

// One ConvLSTM step: z = conv(x,Wk)+conv(h,Uk)+b; i,f,o=hsig; c'=f*c+i*tanh(zc);
// h'=o*tanh(c'). Writes h' to h_next, c' in place, relu(h') to out_seq (if set).
template<int CIN, int KS>
__global__ __launch_bounds__(NTHREADS)
void convlstm_step(
    const float* __restrict__ x, long x_bstride,
    const float* __restrict__ h_prev,
    float* __restrict__ c_state,
    const float* __restrict__ Wk,
    const float* __restrict__ Uk,
    const float* __restrict__ bias,
    float* __restrict__ h_next,
    float* __restrict__ out_seq, long out_bstride)
{
    __shared__ __align__(16) float lds[(TILE + KS - 1) * 64];

    const int tid = threadIdx.x;
    const int cl = tid & 63;       // filter index f
    const int pg = tid >> 6;       // pixel group (wave-uniform)
    const int bi = blockIdx.x;
    const int batch = bi >> 7;     // 64 rows * 2 tiles = 128 blocks per image
    const int rem = bi & 127;
    const int y = rem >> 1;
    const int x0 = (rem & 1) * TILE;

    float acc[PPT][4];
    #pragma unroll
    for (int p = 0; p < PPT; ++p) {
        #pragma unroll
        for (int g = 0; g < 4; ++g) acc[p][g] = bias[g * 64 + cl];
    }

    conv_accum<CIN, KS>(x + (size_t)batch * x_bstride, Wk, acc, lds, y, x0, cl, pg);
    conv_accum<FC, KS>(h_prev + (size_t)batch * (HH * WW * FC), Uk, acc, lds, y, x0, cl, pg);

    const long sbase = ((long)batch * HH * WW + (long)y * WW + x0) * FC;
    const long obase = (long)batch * out_bstride + ((long)y * WW + x0) * FC;
    #pragma unroll
    for (int p = 0; p < PPT; ++p) {
        int px = pg * PPT + p;
        long idx = sbase + (long)px * FC + cl;
        float zi = acc[p][0], zf = acc[p][1], zc = acc[p][2], zo = acc[p][3];
        float ig = hsig(zi);
        float fg = hsig(zf);
        float og = hsig(zo);
        float cp = c_state[idx];
        float cn = fg * cp + ig * tanhf(zc);
        float hn = og * tanhf(cn);
        c_state[idx] = cn;
        h_next[idx] = hn;
        if (out_seq != nullptr)
            out_seq[obase + (long)px * FC + cl] = fmaxf(hn, 0.0f);
    }
}

// Path-B epilogue: out[b, t, ...] = relu(h[b, ...])
__global__ void relu_copy(const float* __restrict__ h, float* __restrict__ out,
                          long out_bstride)
{
    long i = (long)blockIdx.x * NTHREADS + threadIdx.x;   // 0 .. 2^21-1
    long b = i >> 18;            // HH*WW*FC = 262144 = 2^18
    long r = i & 262143;
    out[b * out_bstride + r] = fmaxf(h[i], 0.0f);
}

extern "C" void kernel_launch(void* const* d_in, const int* in_sizes, int n_in,
                              void* d_out, int out_size, void* d_ws, size_t ws_size,
                              hipStream_t stream) {
    const float* x   = (const float*)d_in[0];   // [8,10,64,64,32]
    const float* Wk1 = (const float*)d_in[1];   // [5,5,32,256]
    const float* Uk1 = (const float*)d_in[2];   // [5,5,64,256]
    const float* b1  = (const float*)d_in[3];   // [256]
    const float* Wk2 = (const float*)d_in[4];   // [3,3,64,256]
    const float* Uk2 = (const float*)d_in[5];   // [3,3,64,256]
    const float* b2  = (const float*)d_in[6];   // [256]
    float* out = (float*)d_out;                 // [8,10,64,64,64]

    const long S  = (long)8 * HH * WW * FC;     // state elems = 2,097,152
    const long xT = (long)HH * WW * 32;         // x t-stride
    const long xB = 10 * xT;                    // x batch-stride
    const long oT = (long)HH * WW * FC;         // seq t-stride
    const long oB = 10 * oT;                    // seq batch-stride

    float* h_a   = (float*)d_ws;
    float* h_b   = h_a + S;
    float* c_s   = h_b + S;
    float* h1seq = c_s + S;

    const size_t need = (size_t)(3 * S + 10 * S) * sizeof(float); // 109 MB
    const bool big = (ws_size >= need);
    float* seq1 = big ? h1seq : out;   // Path B: stash layer-1 relu seq in d_out

    // ---- layer 1 (Cin=32, 5x5) ----
    hipMemsetAsync(h_a, 0, S * sizeof(float), stream);
    hipMemsetAsync(c_s, 0, S * sizeof(float), stream);
    float* hc = h_a;
    float* hn = h_b;
    for (int t = 0; t < 10; ++t) {
        convlstm_step<32, 5><<<dim3(1024), dim3(NTHREADS), 0, stream>>>(
            x + t * xT, xB, hc, c_s, Wk1, Uk1, b1, hn, seq1 + t * oT, oB);
        float* tmp = hc; hc = hn; hn = tmp;
    }

    // ---- layer 2 (Cin=64, 3x3) ----
    hipMemsetAsync(hc, 0, S * sizeof(float), stream);
    hipMemsetAsync(c_s, 0, S * sizeof(float), stream);
    for (int t = 0; t < 10; ++t) {
        convlstm_step<64, 3><<<dim3(1024), dim3(NTHREADS), 0, stream>>>(
            seq1 + t * oT, oB, hc, c_s, Wk2, Uk2, b2, hn,
            big ? (out + t * oT) : nullptr, oB);
        if (!big)
            relu_copy<<<dim3(8192), dim3(NTHREADS), 0, stream>>>(hn, out + t * oT, oB);
        float* tmp = hc; hc = hn; hn = tmp;
    }
}

// Round 2
// 2174.240 us; speedup vs baseline: 3.6673x; 3.6673x over previous
//
#include <hip/hip_runtime.h>
#include <cstdint>
#include <cmath>

// ConvLSTM2D x2, B=8 T=10 H=W=64 Cin=32 F=64, split-bf16 MFMA implicit GEMM.
// z = conv(x,Wk)+conv(h,Uk)+b via v_mfma_f32_16x16x32_bf16 with hi/lo split
// (3 MFMAs per product) for fp32-like accuracy. Block = 1 image row (64 px)
// x 256 gate channels; 4 waves = 4 filter groups; wave = 4 M-tiles x 4 gates.
// Weights repacked once per launch into B-fragment layout (bf16 hi/lo).

#define NT 256

typedef __attribute__((ext_vector_type(8))) short short8;
typedef __attribute__((ext_vector_type(4))) float f32x4;

__device__ __forceinline__ float hsig(float v) {
    // Keras hard_sigmoid: clip(0.2*x + 0.5, 0, 1)
    return fminf(fmaxf(fmaf(v, 0.2f, 0.5f), 0.0f), 1.0f);
}

__device__ __forceinline__ short bf16rnd(float f) {
    union { float f; unsigned u; } a; a.f = f;
    return (short)((a.u + 0x7FFFu + ((a.u >> 16) & 1u)) >> 16);
}

__device__ __forceinline__ void split_bf16(float f, short& h, short& l) {
    h = bf16rnd(f);
    union { unsigned u; float f; } b; b.u = ((unsigned)(unsigned short)h) << 16;
    l = bf16rnd(f - b.f);
}

// One 'SAME' conv accumulated into acc[g][mt] via MFMA.
// I: [64,64,CIN] (one batch image). Bpk: packed weights
// [tap][chunk][g][fg][lane]{8 hi,8 lo} shorts. Row y, full 64 columns.
template<int CIN, int KS>
__device__ __forceinline__ void conv_mfma(
    const float* __restrict__ I,
    const short* __restrict__ Bpk,
    f32x4 (&acc)[4][4],
    short* lh, short* ll,
    int y, int fg, int lane, int tid)
{
    constexpr int CH   = CIN / 32;
    constexpr int PAD  = KS / 2;
    constexpr int COLS = 64 + 2 * PAD;
    constexpr int SC   = CIN + 8;          // 16B-aligned frag reads, ~2-way banks
    constexpr int CP   = CIN / 2;

    for (int ky = 0; ky < KS; ++ky) {
        int yin = y + ky - PAD;
        if (yin < 0 || yin >= 64) continue;          // block-uniform
        __syncthreads();                              // prior LDS readers done
        const float* row = I + (size_t)yin * 64 * CIN;
        for (int idx = tid; idx < COLS * CP; idx += NT) {
            int col = idx / CP;                       // CP is pow2
            int cp  = idx - col * CP;
            int g   = col - PAD;
            float2 v;
            if (g >= 0 && g < 64) v = *(const float2*)&row[g * CIN + 2 * cp];
            else { v.x = 0.0f; v.y = 0.0f; }
            short h0, l0, h1, l1;
            split_bf16(v.x, h0, l0);
            split_bf16(v.y, h1, l1);
            unsigned ph = (unsigned)(unsigned short)h0 | ((unsigned)(unsigned short)h1 << 16);
            unsigned pl = (unsigned)(unsigned short)l0 | ((unsigned)(unsigned short)l1 << 16);
            ((unsigned*)lh)[(col * SC) / 2 + cp] = ph;
            ((unsigned*)ll)[(col * SC) / 2 + cp] = pl;
        }
        __syncthreads();

        for (int kx = 0; kx < KS; ++kx) {
            int tap = ky * KS + kx;
            #pragma unroll
            for (int ch = 0; ch < CH; ++ch) {
                int choff = ch * 32 + (lane >> 4) * 8;   // k = c within chunk
                short8 ah[4], al[4];
                #pragma unroll
                for (int mt = 0; mt < 4; ++mt) {
                    int col = mt * 16 + (lane & 15) + kx;
                    ah[mt] = *(const short8*)&lh[col * SC + choff];
                    al[mt] = *(const short8*)&ll[col * SC + choff];
                }
                const short* bp = Bpk + ((size_t)((tap * CH + ch) * 16 + fg)) * 1024
                                + lane * 16;
                #pragma unroll
                for (int g = 0; g < 4; ++g) {
                    short8 bh = *(const short8*)bp;
                    short8 bl = *(const short8*)(bp + 8);
                    bp += 4096;                           // g-stride = 4 units
                    #pragma unroll
                    for (int mt = 0; mt < 4; ++mt) {
                        acc[g][mt] = __builtin_amdgcn_mfma_f32_16x16x32_bf16(
                            ah[mt], bh, acc[g][mt], 0, 0, 0);
                        acc[g][mt] = __builtin_amdgcn_mfma_f32_16x16x32_bf16(
                            al[mt], bh, acc[g][mt], 0, 0, 0);
                        acc[g][mt] = __builtin_amdgcn_mfma_f32_16x16x32_bf16(
                            ah[mt], bl, acc[g][mt], 0, 0, 0);
                    }
                }
            }
        }
    }
}

// One ConvLSTM step for all batches' row y. Grid: 8*64 = 512 blocks.
template<int CIN, int KS>
__global__ __launch_bounds__(NT, 2)
void convlstm_step(
    const float* __restrict__ xt, long x_bstride,
    const float* __restrict__ h_prev,
    float* __restrict__ c_state,
    const short* __restrict__ Wpk,
    const short* __restrict__ Upk,
    const float* __restrict__ bias,
    float* __restrict__ h_next,
    float* __restrict__ out_seq, long out_bstride)
{
    __shared__ __align__(16) short lh[4896];   // max: 68 cols * 72 stride
    __shared__ __align__(16) short ll[4896];

    const int tid  = threadIdx.x;
    const int lane = tid & 63;
    const int fg   = tid >> 6;                 // filter group = wave id
    const int batch = blockIdx.x >> 6;
    const int y     = blockIdx.x & 63;

    f32x4 acc[4][4];
    #pragma unroll
    for (int g = 0; g < 4; ++g)
        #pragma unroll
        for (int mt = 0; mt < 4; ++mt)
            #pragma unroll
            for (int r = 0; r < 4; ++r) acc[g][mt][r] = 0.0f;

    conv_mfma<CIN, KS>(xt + (size_t)batch * x_bstride, Wpk, acc, lh, ll, y, fg, lane, tid);
    conv_mfma<64,  KS>(h_prev + (size_t)batch * 262144, Upk, acc, lh, ll, y, fg, lane, tid);

    const int fl = fg * 16 + (lane & 15);
    const float b_i = bias[fl];
    const float b_f = bias[64 + fl];
    const float b_c = bias[128 + fl];
    const float b_o = bias[192 + fl];
    const long sb = (long)(batch * 64 + y) * 4096 + fl;
    const long ob = (long)batch * out_bstride + (long)y * 4096 + fl;

    #pragma unroll
    for (int mt = 0; mt < 4; ++mt) {
        #pragma unroll
        for (int r = 0; r < 4; ++r) {
            int col = mt * 16 + (lane >> 4) * 4 + r;   // pixel column
            long idx = sb + (long)col * 64;
            float zi = acc[0][mt][r] + b_i;
            float zf = acc[1][mt][r] + b_f;
            float zc = acc[2][mt][r] + b_c;
            float zo = acc[3][mt][r] + b_o;
            float ig = hsig(zi);
            float fgt = hsig(zf);
            float og = hsig(zo);
            float cp = c_state[idx];
            float cn = fgt * cp + ig * tanhf(zc);
            float hn = og * tanhf(cn);
            c_state[idx] = cn;
            h_next[idx] = hn;
            if (out_seq != nullptr)
                out_seq[ob + (long)col * 64] = fmaxf(hn, 0.0f);
        }
    }
}

// Repack fp32 weights [KS,KS,CIN,256] -> B-fragment hi/lo layout:
// dst[unit][lane]{8 hi, 8 lo}, unit = (tap*CH + ch)*16 + g*4 + fg,
// element: k = ch*32 + (lane>>4)*8 + j  (input channel), n = lane&15,
// gate channel = g*64 + fg*16 + n.
__global__ void repack(const float* __restrict__ src, short* __restrict__ dst,
                       int KS, int CH)
{
    int total = KS * KS * CH * 16 * 64;
    int t = blockIdx.x * NT + threadIdx.x;
    if (t >= total) return;
    int u = t >> 6, lane = t & 63;
    int tap = u / (CH * 16);
    int rem = u - tap * (CH * 16);
    int ch = rem >> 4;
    int gfg = rem & 15;
    int g = gfg >> 2, fgp = gfg & 3;
    int CIN = CH * 32;
    int n = lane & 15, q = lane >> 4;
    short* d = dst + (size_t)u * 1024 + lane * 16;
    int gc = g * 64 + fgp * 16 + n;
    for (int j = 0; j < 8; ++j) {
        int c = ch * 32 + q * 8 + j;
        float w = src[((size_t)tap * CIN + c) * 256 + gc];
        short h, l;
        split_bf16(w, h, l);
        d[j] = h;
        d[8 + j] = l;
    }
}

// Path-B epilogue: out[b, t, ...] = relu(h[b, ...])
__global__ void relu_copy(const float* __restrict__ h, float* __restrict__ out,
                          long out_bstride)
{
    long i = (long)blockIdx.x * NT + threadIdx.x;    // 0 .. 2^21-1
    long b = i >> 18;                                // 64*64*64 = 262144
    long r = i & 262143;
    out[b * out_bstride + r] = fmaxf(h[i], 0.0f);
}

extern "C" void kernel_launch(void* const* d_in, const int* in_sizes, int n_in,
                              void* d_out, int out_size, void* d_ws, size_t ws_size,
                              hipStream_t stream) {
    const float* x   = (const float*)d_in[0];   // [8,10,64,64,32]
    const float* Wk1 = (const float*)d_in[1];   // [5,5,32,256]
    const float* Uk1 = (const float*)d_in[2];   // [5,5,64,256]
    const float* b1  = (const float*)d_in[3];   // [256]
    const float* Wk2 = (const float*)d_in[4];   // [3,3,64,256]
    const float* Uk2 = (const float*)d_in[5];   // [3,3,64,256]
    const float* b2  = (const float*)d_in[6];   // [256]
    float* out = (float*)d_out;                 // [8,10,64,64,64]

    const long S  = (long)8 * 64 * 64 * 64;     // state elems = 2,097,152
    const long xT = (long)64 * 64 * 32;         // x t-stride
    const long xB = 10 * xT;                    // x batch-stride
    const long oT = (long)64 * 64 * 64;         // seq t-stride
    const long oB = 10 * oT;                    // seq batch-stride

    float* h_a = (float*)d_ws;
    float* h_b = h_a + S;
    float* c_s = h_b + S;
    short* Wp1 = (short*)(c_s + S);
    short* Up1 = Wp1 + 25 * 1 * 16 * 1024;      // 409600 shorts
    short* Wp2 = Up1 + 25 * 2 * 16 * 1024;      // 819200
    short* Up2 = Wp2 + 9 * 2 * 16 * 1024;       // 294912
    short* pend = Up2 + 9 * 2 * 16 * 1024;      // 294912
    uintptr_t so = ((uintptr_t)pend + 15) & ~(uintptr_t)15;
    float* h1seq = (float*)so;
    size_t need = (size_t)((char*)(h1seq + 10 * S) - (char*)d_ws);
    const bool big = (ws_size >= need);
    float* seq1 = big ? h1seq : out;            // Path B: stash seq1 in d_out

    // ---- repack weights (every call; idempotent) ----
    repack<<<dim3((25 * 1 * 16 * 64 + NT - 1) / NT), dim3(NT), 0, stream>>>(Wk1, Wp1, 5, 1);
    repack<<<dim3((25 * 2 * 16 * 64 + NT - 1) / NT), dim3(NT), 0, stream>>>(Uk1, Up1, 5, 2);
    repack<<<dim3((9 * 2 * 16 * 64 + NT - 1) / NT), dim3(NT), 0, stream>>>(Wk2, Wp2, 3, 2);
    repack<<<dim3((9 * 2 * 16 * 64 + NT - 1) / NT), dim3(NT), 0, stream>>>(Uk2, Up2, 3, 2);

    // ---- layer 1 (Cin=32, 5x5) ----
    hipMemsetAsync(h_a, 0, S * sizeof(float), stream);
    hipMemsetAsync(c_s, 0, S * sizeof(float), stream);
    float* hc = h_a;
    float* hn = h_b;
    for (int t = 0; t < 10; ++t) {
        convlstm_step<32, 5><<<dim3(512), dim3(NT), 0, stream>>>(
            x + t * xT, xB, hc, c_s, Wp1, Up1, b1, hn, seq1 + t * oT, oB);
        float* tmp = hc; hc = hn; hn = tmp;
    }

    // ---- layer 2 (Cin=64, 3x3) ----
    hipMemsetAsync(hc, 0, S * sizeof(float), stream);
    hipMemsetAsync(c_s, 0, S * sizeof(float), stream);
    for (int t = 0; t < 10; ++t) {
        convlstm_step<64, 3><<<dim3(512), dim3(NT), 0, stream>>>(
            seq1 + t * oT, oB, hc, c_s, Wp2, Up2, b2, hn,
            big ? (out + t * oT) : nullptr, oB);
        if (!big)
            relu_copy<<<dim3(8192), dim3(NT), 0, stream>>>(hn, out + t * oT, oB);
        float* tmp = hc; hc = hn; hn = tmp;
    }
}

// Round 3
// 1946.319 us; speedup vs baseline: 4.0967x; 1.1171x over previous
//
#include <hip/hip_runtime.h>
#include <cstdint>
#include <cmath>

// ConvLSTM2D x2, B=8 T=10 H=W=64 Cin=32 F=64, split-bf16 MFMA implicit GEMM.
// Round 3: all conv inputs live as pre-split hi/lo bf16 "planes"
// ([pixel]{CIN hi shorts, CIN lo shorts}); staging is a pure uint4 copy with
// register-relay prefetch (load ky+1 before computing ky); LDS pixel stride
// 2*CIN+8 shorts (granule stride 1 -> near-conflict-free frag reads).
// h state is stored as planes; L1 writes relu'd seq planes into d_out, L2
// consumes slot t then relu_copy overwrites slot t with final fp32.

#define NT 256

typedef __attribute__((ext_vector_type(8))) short short8;
typedef __attribute__((ext_vector_type(4))) float f32x4;

__device__ __forceinline__ float hsig(float v) {
    return fminf(fmaxf(fmaf(v, 0.2f, 0.5f), 0.0f), 1.0f);
}

__device__ __forceinline__ short bf16rnd(float f) {
    union { float f; unsigned u; } a; a.f = f;
    return (short)((a.u + 0x7FFFu + ((a.u >> 16) & 1u)) >> 16);
}

__device__ __forceinline__ void split_bf16(float f, short& h, short& l) {
    h = bf16rnd(f);
    union { unsigned u; float f; } b; b.u = ((unsigned)(unsigned short)h) << 16;
    l = bf16rnd(f - b.f);
}

__device__ __forceinline__ float from_bf16(short s) {
    union { unsigned u; float f; } b; b.u = ((unsigned)(unsigned short)s) << 16;
    return b.f;
}

// One 'SAME' conv accumulated into acc[g][mt] via MFMA.
// P: hi/lo plane image [64*64][2*CIN shorts]. Bpk: packed weights
// [tap][ch][g][fg][lane]{8 hi,8 lo}. Row y, full 64 columns.
template<int CIN, int KS>
__device__ __forceinline__ void conv_mfma(
    const short* __restrict__ P,
    const short* __restrict__ Bpk,
    f32x4 (&acc)[4][4],
    short* lds,
    int y, int fg, int lane, int tid)
{
    constexpr int PAD   = KS / 2;
    constexpr int COLS  = 64 + 2 * PAD;
    constexpr int PST   = 2 * CIN + 8;      // shorts; granule stride 1 mod 8
    constexpr int CH    = CIN / 32;
    constexpr int VPP   = (2 * CIN) / 8;    // uint4 chunks per pixel (pow2)
    constexpr int NLOAD = COLS * VPP;
    constexpr int NV    = (NLOAD + NT - 1) / NT;

    uint4 vals[NV];

    // prefetch helper: row (y + ky - PAD), zero-filled outside the image
    auto load_row = [&](int ky) {
        int yin = y + ky - PAD;
        const short* rowp = P + (size_t)yin * 64 * 2 * CIN;
        #pragma unroll
        for (int i = 0; i < NV; ++i) {
            int idx = tid + i * NT;
            uint4 z; z.x = 0; z.y = 0; z.z = 0; z.w = 0;
            if (idx < NLOAD) {
                int col = idx / VPP;            // pow2 -> shift
                int v   = idx - col * VPP;
                int g   = col - PAD;
                if (yin >= 0 && yin < 64 && g >= 0 && g < 64)
                    z = *(const uint4*)(rowp + (size_t)g * 2 * CIN + v * 8);
            }
            vals[i] = z;
        }
    };

    load_row(0);
    for (int ky = 0; ky < KS; ++ky) {
        __syncthreads();                        // prior LDS readers done
        #pragma unroll
        for (int i = 0; i < NV; ++i) {
            int idx = tid + i * NT;
            if (idx < NLOAD) {
                int col = idx / VPP;
                int v   = idx - col * VPP;
                *(uint4*)(lds + col * PST + v * 8) = vals[i];
            }
        }
        __syncthreads();
        if (ky + 1 < KS) load_row(ky + 1);      // issue loads, overlap compute

        int yin = y + ky - PAD;
        if (yin >= 0 && yin < 64) {             // block-uniform; skip zero rows
            for (int kx = 0; kx < KS; ++kx) {
                int tap = ky * KS + kx;
                #pragma unroll
                for (int ch = 0; ch < CH; ++ch) {
                    int choff = ch * 32 + ((lane >> 4) & 3) * 8;
                    short8 ah[4], al[4];
                    #pragma unroll
                    for (int mt = 0; mt < 4; ++mt) {
                        int col = mt * 16 + (lane & 15) + kx;
                        const short* base = lds + col * PST + choff;
                        ah[mt] = *(const short8*)base;
                        al[mt] = *(const short8*)(base + CIN);
                    }
                    const short* bp = Bpk
                        + ((size_t)((tap * CH + ch) * 16 + fg)) * 1024
                        + lane * 16;
                    #pragma unroll
                    for (int g = 0; g < 4; ++g) {
                        short8 bh = *(const short8*)bp;
                        short8 bl = *(const short8*)(bp + 8);
                        bp += 4096;             // g-stride = 4 units
                        #pragma unroll
                        for (int mt = 0; mt < 4; ++mt) {
                            acc[g][mt] = __builtin_amdgcn_mfma_f32_16x16x32_bf16(
                                ah[mt], bh, acc[g][mt], 0, 0, 0);
                            acc[g][mt] = __builtin_amdgcn_mfma_f32_16x16x32_bf16(
                                al[mt], bh, acc[g][mt], 0, 0, 0);
                            acc[g][mt] = __builtin_amdgcn_mfma_f32_16x16x32_bf16(
                                ah[mt], bl, acc[g][mt], 0, 0, 0);
                        }
                    }
                }
            }
        }
    }
}

// One ConvLSTM step for all batches' row y. Grid: 8*64 = 512 blocks.
// x planes CIN_X channels; h planes 64 channels. h_next written as planes.
// If WRITE_SEQ: relu(h) written as planes to seq slot (d_out region).
template<int CIN_X, int KS, bool WRITE_SEQ>
__global__ __launch_bounds__(NT, 2)
void convlstm_step(
    const short* __restrict__ xp, long xp_bstride,     // shorts
    const short* __restrict__ h_prev,                  // planes [32768 px][128]
    float* __restrict__ c_state,
    const short* __restrict__ Wpk,
    const short* __restrict__ Upk,
    const float* __restrict__ bias,
    short* __restrict__ h_next,
    short* __restrict__ seq, long seq_bstride)         // shorts
{
    __shared__ __align__(16) short lds[9248];          // 68 cols * 136 stride

    const int tid  = threadIdx.x;
    const int lane = tid & 63;
    const int fg   = tid >> 6;
    const int q    = (lane >> 4) & 3;
    const int batch = blockIdx.x >> 6;
    const int y     = blockIdx.x & 63;

    f32x4 acc[4][4];
    #pragma unroll
    for (int g = 0; g < 4; ++g)
        #pragma unroll
        for (int mt = 0; mt < 4; ++mt)
            #pragma unroll
            for (int r = 0; r < 4; ++r) acc[g][mt][r] = 0.0f;

    conv_mfma<CIN_X, KS>(xp + (size_t)batch * xp_bstride, Wpk, acc, lds, y, fg, lane, tid);
    conv_mfma<64,    KS>(h_prev + (size_t)batch * 4096 * 128, Upk, acc, lds, y, fg, lane, tid);

    const int fl = fg * 16 + (lane & 15);
    const float b_i = bias[fl];
    const float b_f = bias[64 + fl];
    const float b_c = bias[128 + fl];
    const float b_o = bias[192 + fl];

    const long pixbase = (long)batch * 4096 + (long)y * 64;     // pixel index
    const long cb = pixbase * 64 + fl;
    const long sb = (long)batch * seq_bstride + ((long)y * 64) * 128 + fl;

    #pragma unroll
    for (int mt = 0; mt < 4; ++mt) {
        #pragma unroll
        for (int r = 0; r < 4; ++r) {
            int col = mt * 16 + q * 4 + r;          // pixel column
            long cidx = cb + (long)col * 64;
            float zi = acc[0][mt][r] + b_i;
            float zf = acc[1][mt][r] + b_f;
            float zc = acc[2][mt][r] + b_c;
            float zo = acc[3][mt][r] + b_o;
            float ig = hsig(zi);
            float fgt = hsig(zf);
            float og = hsig(zo);
            float cp = c_state[cidx];
            float cn = fgt * cp + ig * tanhf(zc);
            float hn = og * tanhf(cn);
            c_state[cidx] = cn;

            short hh, hl;
            split_bf16(hn, hh, hl);
            long hoff = (pixbase + col) * 128 + fl;
            h_next[hoff]      = hh;
            h_next[hoff + 64] = hl;
            if (WRITE_SEQ) {
                bool pos = hn > 0.0f;
                seq[sb + (long)col * 128]      = pos ? hh : (short)0;
                seq[sb + (long)col * 128 + 64] = pos ? hl : (short)0;
            }
        }
    }
}

// fp32 x [Npix][32] -> hi/lo planes [Npix]{32 hi,32 lo}. One thread = 4 ch.
__global__ void convert_planes32(const float4* __restrict__ src,
                                 unsigned* __restrict__ dst, int n4)
{
    int t = blockIdx.x * NT + threadIdx.x;
    if (t >= n4) return;
    int pix = t >> 3;                  // 8 float4 per pixel
    int c4  = t & 7;
    float4 v = src[t];
    short h0, l0, h1, l1, h2, l2, h3, l3;
    split_bf16(v.x, h0, l0);
    split_bf16(v.y, h1, l1);
    split_bf16(v.z, h2, l2);
    split_bf16(v.w, h3, l3);
    unsigned* p = dst + (size_t)pix * 32;      // 32 uints per pixel
    p[c4 * 2]      = (unsigned)(unsigned short)h0 | ((unsigned)(unsigned short)h1 << 16);
    p[c4 * 2 + 1]  = (unsigned)(unsigned short)h2 | ((unsigned)(unsigned short)h3 << 16);
    p[16 + c4 * 2]     = (unsigned)(unsigned short)l0 | ((unsigned)(unsigned short)l1 << 16);
    p[16 + c4 * 2 + 1] = (unsigned)(unsigned short)l2 | ((unsigned)(unsigned short)l3 << 16);
}

// Repack fp32 weights [KS,KS,CIN,256] -> B-fragment hi/lo layout (as R2).
__global__ void repack(const float* __restrict__ src, short* __restrict__ dst,
                       int KS, int CH)
{
    int total = KS * KS * CH * 16 * 64;
    int t = blockIdx.x * NT + threadIdx.x;
    if (t >= total) return;
    int u = t >> 6, lane = t & 63;
    int tap = u / (CH * 16);
    int rem = u - tap * (CH * 16);
    int ch = rem >> 4;
    int gfg = rem & 15;
    int g = gfg >> 2, fgp = gfg & 3;
    int CIN = CH * 32;
    int n = lane & 15, qq = lane >> 4;
    short* d = dst + (size_t)u * 1024 + lane * 16;
    int gc = g * 64 + fgp * 16 + n;
    for (int j = 0; j < 8; ++j) {
        int c = ch * 32 + qq * 8 + j;
        float w = src[((size_t)tap * CIN + c) * 256 + gc];
        short h, l;
        split_bf16(w, h, l);
        d[j] = h;
        d[8 + j] = l;
    }
}

// out[b, t, pix, c] = relu(hi/lo planes h)
__global__ void relu_copy(const short* __restrict__ hp, float* __restrict__ out,
                          long out_bstride)
{
    long i = (long)blockIdx.x * NT + threadIdx.x;   // 0 .. 2^21-1
    long pix = i >> 6;
    int c = (int)(i & 63);
    float f = from_bf16(hp[pix * 128 + c]) + from_bf16(hp[pix * 128 + 64 + c]);
    long b = pix >> 12;                             // 4096 px per image
    long within = (pix & 4095) * 64 + c;
    out[b * out_bstride + within] = fmaxf(f, 0.0f);
}

extern "C" void kernel_launch(void* const* d_in, const int* in_sizes, int n_in,
                              void* d_out, int out_size, void* d_ws, size_t ws_size,
                              hipStream_t stream) {
    const float* x   = (const float*)d_in[0];   // [8,10,64,64,32]
    const float* Wk1 = (const float*)d_in[1];   // [5,5,32,256]
    const float* Uk1 = (const float*)d_in[2];   // [5,5,64,256]
    const float* b1  = (const float*)d_in[3];   // [256]
    const float* Wk2 = (const float*)d_in[4];   // [3,3,64,256]
    const float* Uk2 = (const float*)d_in[5];   // [3,3,64,256]
    const float* b2  = (const float*)d_in[6];   // [256]
    float* out = (float*)d_out;                 // [8,10,64,64,64]

    const long S  = (long)8 * 64 * 64 * 64;     // 2,097,152 state elems
    const long oT = (long)64 * 64 * 64;         // out t-stride (floats)
    const long oB = 10 * oT;                    // out batch-stride (floats)

    // ws layout (shorts/floats): h planes x2, c fp32, packed weights, x planes
    short* h_a = (short*)d_ws;                  // S elems * 2 shorts = 8.4 MB
    short* h_b = h_a + 2 * S;
    float* c_s = (float*)(h_b + 2 * S);         // 8.4 MB
    short* Wp1 = (short*)(c_s + S);
    short* Up1 = Wp1 + 25 * 1 * 16 * 1024;      // 409600 shorts
    short* Wp2 = Up1 + 25 * 2 * 16 * 1024;      // 819200
    short* Up2 = Wp2 + 9 * 2 * 16 * 1024;       // 294912
    short* x1p = Up2 + 9 * 2 * 16 * 1024;       // x planes: 8*10*4096*64 shorts
    const long x1pN = (long)8 * 10 * 4096 * 64; // shorts (41.9 MB)
    (void)x1pN; (void)ws_size;

    // ---- one-time per call: convert x, repack weights ----
    {
        int n4 = 8 * 10 * 4096 * 8;             // float4 groups in x
        convert_planes32<<<dim3((n4 + NT - 1) / NT), dim3(NT), 0, stream>>>(
            (const float4*)x, (unsigned*)x1p, n4);
    }
    repack<<<dim3((25 * 1 * 16 * 64 + NT - 1) / NT), dim3(NT), 0, stream>>>(Wk1, Wp1, 5, 1);
    repack<<<dim3((25 * 2 * 16 * 64 + NT - 1) / NT), dim3(NT), 0, stream>>>(Uk1, Up1, 5, 2);
    repack<<<dim3((9 * 2 * 16 * 64 + NT - 1) / NT), dim3(NT), 0, stream>>>(Wk2, Wp2, 3, 2);
    repack<<<dim3((9 * 2 * 16 * 64 + NT - 1) / NT), dim3(NT), 0, stream>>>(Uk2, Up2, 3, 2);

    short* seqs = (short*)d_out;                // seq planes live in d_out slots

    // ---- layer 1 (x planes CIN=32, 5x5) ----
    hipMemsetAsync(h_a, 0, (size_t)S * 4, stream);
    hipMemsetAsync(c_s, 0, (size_t)S * 4, stream);
    short* hc = h_a;
    short* hn = h_b;
    const long x1T = (long)4096 * 64;           // x plane t-stride (shorts)
    const long x1B = 10 * x1T;                  // batch stride (shorts)
    for (int t = 0; t < 10; ++t) {
        convlstm_step<32, 5, true><<<dim3(512), dim3(NT), 0, stream>>>(
            x1p + t * x1T, x1B, hc, c_s, Wp1, Up1, b1, hn,
            seqs + t * oT * 2, oB * 2);
        short* tmp = hc; hc = hn; hn = tmp;
    }

    // ---- layer 2 (x = seq planes CIN=64, 3x3) ----
    hipMemsetAsync(hc, 0, (size_t)S * 4, stream);
    hipMemsetAsync(c_s, 0, (size_t)S * 4, stream);
    for (int t = 0; t < 10; ++t) {
        convlstm_step<64, 3, false><<<dim3(512), dim3(NT), 0, stream>>>(
            seqs + t * oT * 2, oB * 2, hc, c_s, Wp2, Up2, b2, hn,
            nullptr, 0);
        relu_copy<<<dim3(8192), dim3(NT), 0, stream>>>(hn, out + t * oT, oB);
        short* tmp = hc; hc = hn; hn = tmp;
    }
}